// Round 1
// baseline (3924.432 us; speedup 1.0000x reference)
//
#include <hip/hip_runtime.h>
#include <math.h>

// Problem constants (B=4096, T=100, F=13, H=100)
#define B_   4096
#define T_   100
#define F_   13
#define H_   100
#define G4_  400    // 4*H gates
#define K0_  113    // F + H   (layer0 GEMM depth: [x, h0])
#define K1_  200    // 2*H     (layer1 GEMM depth: [h0n, h1])

// d_ws layout (bytes). Total need = 522,432 B (~0.5 MB).
#define O_HIST   0u       // 128 ints (length histogram -> offsets)
#define O_ROWMAP 512u     // 4096 ints (rows sorted by length)
#define O_WT0    17408u   // 113*400 floats, k-major, gate-interleaved
#define O_WT1    198912u  // 200*400 floats
#define O_B0     519168u  // 400 floats (b_ih0+b_hh0, interleaved)
#define O_B1     520832u  // 400 floats

__device__ __forceinline__ float sigmoid_f(float v) {
    return 1.0f / (1.0f + __expf(-v));   // v->-inf: exp=inf -> 0 ; v->+inf: -> 1
}
__device__ __forceinline__ float tanh_f(float v) {
    float e = __expf(2.0f * v);          // saturates correctly at +-inf
    return 1.0f - 2.0f / (e + 1.0f);
}

// ---------------- prep: counting sort of rows by length ----------------
__global__ void k_hist(const int* __restrict__ len, int* __restrict__ hist) {
    int b = blockIdx.x * blockDim.x + threadIdx.x;
    if (b < B_) atomicAdd(&hist[len[b]], 1);
}

__global__ void k_scan(int* __restrict__ hist) {
    if (threadIdx.x == 0 && blockIdx.x == 0) {
        int acc = 0;
        for (int l = 0; l <= 100; ++l) { int c = hist[l]; hist[l] = acc; acc += c; }
    }
}

__global__ void k_scatter(const int* __restrict__ len, int* __restrict__ hist,
                          int* __restrict__ rowmap) {
    int b = blockIdx.x * blockDim.x + threadIdx.x;
    if (b < B_) {
        int pos = atomicAdd(&hist[len[b]], 1);
        rowmap[pos] = b;  // within-bin order nondeterministic; results row-indexed, so fine
    }
}

// ---------------- prep: transpose + gate-interleave weights ----------------
// wt[k][4*j+ty] = W[ty*100+j][k-part], ty in {i,f,g,o}. So the 8 consecutive
// columns a thread owns are gates {j0,j0+1} x {i,f,g,o}: the GEMM thread can do
// the pointwise cell update itself (c stays in registers, z never hits LDS).
__global__ void k_prep_w(const float* __restrict__ Wih0, const float* __restrict__ Whh0,
                         const float* __restrict__ bih0, const float* __restrict__ bhh0,
                         const float* __restrict__ Wih1, const float* __restrict__ Whh1,
                         const float* __restrict__ bih1, const float* __restrict__ bhh1,
                         float* __restrict__ wt0, float* __restrict__ wt1,
                         float* __restrict__ bb0, float* __restrict__ bb1) {
    int idx = blockIdx.x * blockDim.x + threadIdx.x;
    if (idx < K0_ * G4_) {
        int k = idx / G4_, c = idx - k * G4_;
        int ty = c & 3, j = c >> 2, row = 100 * ty + j;
        wt0[idx] = (k < F_) ? Wih0[row * F_ + k] : Whh0[row * H_ + (k - F_)];
    }
    if (idx < K1_ * G4_) {
        int k = idx / G4_, c = idx - k * G4_;
        int ty = c & 3, j = c >> 2, row = 100 * ty + j;
        wt1[idx] = (k < H_) ? Wih1[row * H_ + k] : Whh1[row * H_ + (k - H_)];
    }
    if (idx < G4_) {
        int ty = idx & 3, j = idx >> 2, row = 100 * ty + j;
        bb0[idx] = bih0[row] + bhh0[row];
        bb1[idx] = bih1[row] + bhh1[row];
    }
}

// ---------------- main persistent LSTM kernel ----------------
// 256 blocks x 16 rows. Thread tile: 4 rows x 8 interleaved gate-cols (200 of
// 256 threads active in GEMM/update phases). h kept K-major in LDS for float4
// row loads; weights streamed float4 from the transposed global copy (L2-hot).
template <int K>
__device__ __forceinline__ void gemm_tile(const float (*__restrict__ hT)[16],
                                          const float* __restrict__ wt,
                                          int colbase, int r0,
                                          const float* biasv, float acc[4][8]) {
#pragma unroll
    for (int r = 0; r < 4; r++)
#pragma unroll
        for (int c = 0; c < 8; c++) acc[r][c] = biasv[c];
    const float* wp = wt + colbase;
#pragma unroll 2
    for (int k = 0; k < K; k++) {
        const float4 h4 = *reinterpret_cast<const float4*>(&hT[k][r0]);
        const float4 wa = *reinterpret_cast<const float4*>(wp);
        const float4 wb = *reinterpret_cast<const float4*>(wp + 4);
        wp += G4_;
        float hh[4] = {h4.x, h4.y, h4.z, h4.w};
        float ww[8] = {wa.x, wa.y, wa.z, wa.w, wb.x, wb.y, wb.z, wb.w};
#pragma unroll
        for (int r = 0; r < 4; r++)
#pragma unroll
            for (int c = 0; c < 8; c++) acc[r][c] = fmaf(hh[r], ww[c], acc[r][c]);
    }
}

__global__ __launch_bounds__(256) void k_lstm(
    const float* __restrict__ x, const int* __restrict__ lengths,
    const int* __restrict__ rowmap,
    const float* __restrict__ wt0, const float* __restrict__ wt1,
    const float* __restrict__ bb0, const float* __restrict__ bb1,
    const float* __restrict__ Wfc, const float* __restrict__ bfc,
    float* __restrict__ out) {
    __shared__ __align__(16) float hT0[K0_][16];  // k-major: [0..12]=x_t, [13..112]=h0
    __shared__ __align__(16) float hT1[K1_][16];  // [0..99]=h0n, [100..199]=h1
    __shared__ int sRow[16], sLen[16], sTmax;

    const int tid = threadIdx.x;
    const int blk = blockIdx.x;

    if (tid < 16) {
        int r = rowmap[blk * 16 + tid];
        sRow[tid] = r;
        sLen[tid] = lengths[r];
    }
    for (int i = tid; i < K0_ * 16; i += 256) ((float*)hT0)[i] = 0.0f;
    for (int i = tid; i < K1_ * 16; i += 256) ((float*)hT1)[i] = 0.0f;
    __syncthreads();
    if (tid == 0) {
        int m = 0;
        for (int i = 0; i < 16; i++) m = max(m, sLen[i]);
        sTmax = m;
    }
    __syncthreads();
    const int Tmax = sTmax;

    const bool act = (tid < 200);
    const int rg = tid / 50;          // row-group 0..3
    const int jt = tid % 50;          // j-tile: gates {2jt,2jt+1} x {i,f,g,o}
    const int colbase = 8 * jt;
    const int r0 = 4 * rg;

    float c0[4][2] = {}, c1[4][2] = {};
    float bias0v[8], bias1v[8];
    if (act) {
#pragma unroll
        for (int c = 0; c < 8; c++) { bias0v[c] = bb0[colbase + c]; bias1v[c] = bb1[colbase + c]; }
    }

    const int xr = tid / 13, xk = tid - 13 * xr;
    const bool xact = (tid < 208);
    const float* xbase = xact ? (x + (size_t)sRow[xr] * (T_ * F_) + xk) : x;

    for (int t = 0; t < Tmax; ++t) {
        if (xact) hT0[xk][xr] = xbase[(size_t)t * F_];
        __syncthreads();  // A: x_t + h0 (prev) visible

        float acc[4][8];
        if (act) gemm_tile<K0_>(hT0, wt0, colbase, r0, bias0v, acc);
        __syncthreads();  // B: all GEMM0 reads of hT0 done before h0 writes

        if (act) {
#pragma unroll
            for (int r = 0; r < 4; r++) {
                const int rr = r0 + r;
                if (t < sLen[rr]) {
#pragma unroll
                    for (int jj = 0; jj < 2; jj++) {
                        float zi = acc[r][4 * jj + 0], zf = acc[r][4 * jj + 1];
                        float zg = acc[r][4 * jj + 2], zo = acc[r][4 * jj + 3];
                        float cn = sigmoid_f(zf) * c0[r][jj] + sigmoid_f(zi) * tanh_f(zg);
                        float hn = sigmoid_f(zo) * tanh_f(cn);
                        c0[r][jj] = cn;
                        const int j = 2 * jt + jj;
                        hT0[F_ + j][rr] = hn;   // h0 for next step's layer0
                        hT1[j][rr]      = hn;   // h0n into layer1
                    }
                }
            }
        }
        __syncthreads();  // C: hT1[h0n] ready

        float acc1[4][8];
        if (act) gemm_tile<K1_>(hT1, wt1, colbase, r0, bias1v, acc1);
        __syncthreads();  // D: all GEMM1 reads of hT1 done before h1 writes

        if (act) {
#pragma unroll
            for (int r = 0; r < 4; r++) {
                const int rr = r0 + r;
                if (t < sLen[rr]) {
#pragma unroll
                    for (int jj = 0; jj < 2; jj++) {
                        float zi = acc1[r][4 * jj + 0], zf = acc1[r][4 * jj + 1];
                        float zg = acc1[r][4 * jj + 2], zo = acc1[r][4 * jj + 3];
                        float cn = sigmoid_f(zf) * c1[r][jj] + sigmoid_f(zi) * tanh_f(zg);
                        float hn = sigmoid_f(zo) * tanh_f(cn);
                        c1[r][jj] = cn;
                        hT1[H_ + 2 * jt + jj][rr] = hn;  // frozen at t=len-1 for done rows
                    }
                }
            }
        }
    }
    __syncthreads();

    if (tid < 16) {  // out[b] = W_fc . h1_final + b_fc
        float s = 0.0f;
        for (int j = 0; j < H_; j++) s = fmaf(Wfc[j], hT1[H_ + j][tid], s);
        out[sRow[tid]] = s + bfc[0];
    }
}

// ---------------- launch ----------------
extern "C" void kernel_launch(void* const* d_in, const int* in_sizes, int n_in,
                              void* d_out, int out_size, void* d_ws, size_t ws_size,
                              hipStream_t stream) {
    const float* x    = (const float*)d_in[0];
    const int*   len  = (const int*)d_in[1];
    const float* Wih0 = (const float*)d_in[2];
    const float* Whh0 = (const float*)d_in[3];
    const float* bih0 = (const float*)d_in[4];
    const float* bhh0 = (const float*)d_in[5];
    const float* Wih1 = (const float*)d_in[6];
    const float* Whh1 = (const float*)d_in[7];
    const float* bih1 = (const float*)d_in[8];
    const float* bhh1 = (const float*)d_in[9];
    const float* Wfc  = (const float*)d_in[10];
    const float* bfc  = (const float*)d_in[11];
    float* out = (float*)d_out;

    char* ws = (char*)d_ws;  // needs ~523 KB; ws re-poisoned each call, we fully init what we use
    int*   hist   = (int*)(ws + O_HIST);
    int*   rowmap = (int*)(ws + O_ROWMAP);
    float* wt0    = (float*)(ws + O_WT0);
    float* wt1    = (float*)(ws + O_WT1);
    float* bb0    = (float*)(ws + O_B0);
    float* bb1    = (float*)(ws + O_B1);

    hipMemsetAsync(hist, 0, 512, stream);
    k_hist<<<16, 256, 0, stream>>>(len, hist);
    k_scan<<<1, 64, 0, stream>>>(hist);
    k_scatter<<<16, 256, 0, stream>>>(len, hist, rowmap);
    k_prep_w<<<(K1_ * G4_ + 255) / 256, 256, 0, stream>>>(Wih0, Whh0, bih0, bhh0,
                                                          Wih1, Whh1, bih1, bhh1,
                                                          wt0, wt1, bb0, bb1);
    k_lstm<<<256, 256, 0, stream>>>(x, len, rowmap, wt0, wt1, bb0, bb1, Wfc, bfc, out);
}